// Round 20
// baseline (17542.830 us; speedup 1.0000x reference)
//
#include <hip/hip_runtime.h>

#define S_ 512
#define SCOPE __HIP_MEMORY_SCOPE_AGENT

typedef short bf16x8 __attribute__((ext_vector_type(8)));
typedef float f32x4 __attribute__((ext_vector_type(4)));

__device__ __forceinline__ float sigm(float x) { return 1.f / (1.f + expf(-x)); }
__device__ __forceinline__ float b2f(unsigned short u) {
    return __builtin_bit_cast(float, (unsigned)u << 16);
}
__device__ __forceinline__ unsigned short f2b(float f) {
    unsigned x = __builtin_bit_cast(unsigned, f);
    return (unsigned short)((x + 0x7fffu + ((x >> 16) & 1u)) >> 16);
}
__device__ __forceinline__ float ldcf(const float* p) {
    return __hip_atomic_load(p, __ATOMIC_RELAXED, SCOPE);
}
__device__ __forceinline__ unsigned ldc32(const void* p) {
    return __hip_atomic_load((const unsigned*)p, __ATOMIC_RELAXED, SCOPE);
}
__device__ __forceinline__ unsigned long long ldc64(const void* p) {
    return __hip_atomic_load((const unsigned long long*)p, __ATOMIC_RELAXED, SCOPE);
}
__device__ __forceinline__ void stg32(void* p, unsigned v) {
    __hip_atomic_store((unsigned*)p, v, __ATOMIC_RELAXED, SCOPE);
}
__device__ __forceinline__ void stgf(float* p, float v) {
    __hip_atomic_store(p, v, __ATOMIC_RELAXED, SCOPE);
}
__device__ __forceinline__ bf16x8 frag_c(const unsigned short* p) {
    union { unsigned long long q[2]; bf16x8 v; } u;
    u.q[0] = ldc64(p); u.q[1] = ldc64(p + 4);
    return u.v;
}
__device__ __forceinline__ bf16x8 frag_p(const unsigned short* p) {
    return *(const bf16x8*)p;
}

// one-time grid barrier (prologue only; validated round 9)
__device__ __forceinline__ void gbar(unsigned* bar, int tid, int wg, unsigned n) {
    __syncthreads();
    if (tid == 0) {
        int g = wg >> 5;
        unsigned* gcnt = bar + 64 + g * 32;
        unsigned* ggen = bar + 320 + g * 32;
        unsigned old = __hip_atomic_fetch_add(gcnt, 1u, __ATOMIC_RELAXED, SCOPE);
        if (old == n * 32u - 1u) {
            unsigned rold = __hip_atomic_fetch_add(bar, 1u, __ATOMIC_RELAXED, SCOPE);
            if (rold == n * 8u - 1u) {
                __hip_atomic_store(bar + 32, n, __ATOMIC_RELAXED, SCOPE);
            } else {
                while (__hip_atomic_load(bar + 32, __ATOMIC_RELAXED, SCOPE) < n)
                    __builtin_amdgcn_s_sleep(1);
            }
            __hip_atomic_store(ggen, n, __ATOMIC_RELAXED, SCOPE);
        } else {
            while (__hip_atomic_load(ggen, __ATOMIC_RELAXED, SCOPE) < n)
                __builtin_amdgcn_s_sleep(1);
        }
        asm volatile("" ::: "memory");
    }
    __syncthreads();
}

// flow-sync counters: CNT(0..6)=ck, CNT(7)=cp2, CNT(8..14)=cb, CNT(15..22)=cc
#define CNT(i) (bar + 1024 + (i) * 32)
__device__ __forceinline__ void spin_ge(unsigned* p, unsigned thr) {
    while (__hip_atomic_load(p, __ATOMIC_RELAXED, SCOPE) < thr)
        __builtin_amdgcn_s_sleep(1);
}
__device__ __forceinline__ void bump(unsigned* p) {
    __hip_atomic_fetch_add(p, 1u, __ATOMIC_RELEASE, SCOPE);
}

__global__ __launch_bounds__(512) void fused_all(
        const int* __restrict__ x, const int* __restrict__ taskp,
        const float* __restrict__ embed,
        const float* __restrict__ Wx_t, const float* __restrict__ Wh_t,
        const float* __restrict__ b_t,
        const float* __restrict__ Ws_p1, const float* __restrict__ Ws_p2,
        const float* __restrict__ Us_w,
        const float* __restrict__ Wx_c, const float* __restrict__ Wh_c,
        const float* __restrict__ Wm_c, const float* __restrict__ b_c,
        float* __restrict__ out,
        unsigned short* __restrict__ WTa,  unsigned short* __restrict__ WTp2,
        unsigned short* __restrict__ WTp1, unsigned short* __restrict__ WTc,
        unsigned short* __restrict__ embbf, unsigned short* __restrict__ hbf,
        unsigned short* __restrict__ hmbf,
        float* __restrict__ ctask, float* __restrict__ cmain,
        float* __restrict__ p2w, float* __restrict__ partial,
        float* __restrict__ hNf, unsigned* __restrict__ bar)
{
    __shared__ float smem[8320];
    __shared__ unsigned short swA[64 * 776];
    const int wg = blockIdx.x, tid = threadIdx.x;
    const int lane = tid & 63, wave = tid >> 6;
    const int rowm = lane & 15, ks = lane >> 4;
    const int task = taskp[0];

    // ================= prologue: zero state + bf16 transposed weight build ======
    for (int i = wg * 512 + tid; i < 114688; i += 131072) stg32((unsigned*)hbf + i, 0u);
    for (int i = wg * 512 + tid; i < 16384; i += 131072) stg32((unsigned*)hmbf + i, 0u);
    for (int i = wg * 512 + tid; i < 114688; i += 131072) stgf(ctask + i, 0.f);
    for (int i = wg * 512 + tid; i < 16384; i += 131072) stgf(cmain + i, 0.f);
    for (int i = wg * 512 + tid; i < 2097152; i += 131072) {
        int ts = i >> 12, b = (i >> 7) & 31, ep = i & 127;
        int tok = x[b * S_ + ts];
        const float* s = embed + (size_t)tok * 256 + 2 * ep;
        stg32((unsigned*)embbf + i, (unsigned)f2b(s[0]) | ((unsigned)f2b(s[1]) << 16));
    }
    for (int i = wg * 512 + tid; i < 5505024; i += 131072) {
        int s = i / 24576, r = i % 24576, kp = r >> 6, cg = r & 63;
        int k = s >> 5, nt = s & 31, kk = k + (k >= task);
        int col = ((cg >> 4) << 9) + nt * 16 + (cg & 15);
        int kr = kp * 2;
        const float* src = (kr < 256)
            ? Wx_t + (size_t)kk * 524288 + (size_t)kr * 2048 + col
            : Wh_t + (size_t)kk * 1048576 + (size_t)(kr - 256) * 2048 + col;
        stg32((unsigned*)WTa + (size_t)s * 24576 + cg * 384 + kp,
              (unsigned)f2b(src[0]) | ((unsigned)f2b(src[2048]) << 16));
    }
    for (int i = wg * 512 + tid; i < 196608; i += 131072) {
        int p = i / 24576, r = i % 24576, kp = r >> 6, cg = r & 63;
        int col = p * 64 + cg, kr = kp * 2;
        const float* src = Ws_p2 + (size_t)kr * 512 + col;
        stg32((unsigned*)WTp2 + p * 24576 + cg * 384 + kp,
              (unsigned)f2b(src[0]) | ((unsigned)f2b(src[512]) << 16));
    }
    for (int i = wg * 512 + tid; i < 131072; i += 131072) {
        const float* src = Ws_p1 + 2 * (size_t)i;
        stg32((unsigned*)WTp1 + i, (unsigned)f2b(src[0]) | ((unsigned)f2b(src[1]) << 16));
    }
    for (int i = wg * 512 + tid; i < 1310720; i += 131072) {
        int ntc = i / 10240, r = i % 10240, kp = r >> 4, cg = r & 15;
        int col = ((cg >> 2) << 9) + ntc * 4 + (cg & 3);
        int kr = kp * 2;
        const float* src = (kr < 256) ? Wx_c + (size_t)kr * 2048 + col
                         : (kr < 768) ? Wh_c + (size_t)(kr - 256) * 2048 + col
                                      : Wm_c + (size_t)(kr - 768) * 2048 + col;
        stg32((unsigned*)WTc + ntc * 10240 + cg * 640 + kp,
              (unsigned)f2b(src[0]) | ((unsigned)f2b(src[2048]) << 16));
    }
    gbar(bar, tid, wg, 1);

    if (wg < 232) {
        const unsigned* srcw = (const unsigned*)(wg < 224
            ? WTa + (size_t)wg * 49152 : WTp2 + (size_t)(wg - 224) * 49152);
        for (int i = tid; i < 24576; i += 512) {
            int cg = i / 384, kp = i % 384;
            ((unsigned*)(swA + cg * 776))[kp] = srcw[cg * 384 + kp];
        }
    }
    __syncthreads();

    const int xq = wg & 7, jq = wg >> 3;
    const int kB = jq >> 2, itB = xq + 8 * (jq & 3);

    for (int t = 0; t < S_; ++t) {
        const int old = t & 1, nw = old ^ 1;
        const unsigned short* hb_old = hbf + old * 114688;
        unsigned short* hb_new = hbf + nw * 114688;
        const unsigned short* hm_old = hmbf + old * 16384;
        unsigned short* hm_new = hmbf + nw * 16384;
        const unsigned short* et = embbf + (size_t)t * 8192;
        float* pbuf = partial + (t & 1) * 7168;

        // ================= Phase A: task gates+cell (wg<224) + p2 (224..231) =====
        if (wg < 232) {
            const bool istask = wg < 224;
            // waits: task -> own k-group h(t-1); p2 -> all of C(t-1) (hm)
            {
                unsigned* wp = nullptr; unsigned wthr = 0;
                if (istask) { if (tid == 0) { wp = CNT(wg >> 5); wthr = 32u * t; } }
                else if (tid < 8) { wp = CNT(15 + tid); wthr = 32u * t; }
                if (wp) spin_ge(wp, wthr);
            }
            __syncthreads();
            unsigned short* sh = (unsigned short*)smem;   // [32][520]
            const unsigned short* hsrc = istask ? hb_old + (wg >> 5) * 16384 : hm_old;
            for (int i = tid; i < 4096; i += 512) {
                int row = i >> 7, c8 = i & 127;
                *(unsigned long long*)(sh + row * 520 + c8 * 4) =
                    ldc64(hsrc + row * 512 + c8 * 4);
            }
            __syncthreads();
            f32x4 acc = {0.f, 0.f, 0.f, 0.f};
            if (istask) {
                int k = wg >> 5, nt = wg & 31;
                int mt = wave >> 2, g = wave & 3;
                int b = mt * 16 + rowm;
                const unsigned short* wtp = swA + (g * 16 + rowm) * 776;
                const unsigned short* ep_ = et + b * 256;
                const unsigned short* shb = sh + b * 520;
#pragma unroll
                for (int kt = 0; kt < 24; ++kt) {
                    int ko = kt * 32 + ks * 8;
                    bf16x8 bf = frag_p(wtp + ko);
                    bf16x8 af = (kt < 8) ? frag_p(ep_ + ko) : frag_p(shb + ko - 256);
                    acc = __builtin_amdgcn_mfma_f32_16x16x32_bf16(af, bf, acc, 0, 0, 0);
                }
                __syncthreads();
                float* sg = smem;
#pragma unroll
                for (int r2 = 0; r2 < 4; ++r2)
                    sg[(mt * 16 + (lane >> 4) * 4 + r2) * 64 + g * 16 + rowm] = acc[r2];
                __syncthreads();
                {
                    int b2 = tid >> 4, hc = tid & 15;
                    int kk = k + (k >= task);
                    const float* bb = b_t + kk * 2048 + nt * 16 + hc;
                    float gi = sg[b2 * 64 + hc]      + bb[0];
                    float gf = sg[b2 * 64 + 16 + hc] + bb[512];
                    float gg = sg[b2 * 64 + 32 + hc] + bb[1024];
                    float go = sg[b2 * 64 + 48 + hc] + bb[1536];
                    int cidx = (k * 32 + b2) * 512 + nt * 16 + hc;
                    float cold = ctask[cidx];
                    float cn = sigm(gf) * cold + sigm(gi) * tanhf(gg);
                    float hn = sigm(go) * tanhf(cn);
                    ctask[cidx] = cn;
                    int hbits = (int)f2b(hn);
                    int oth = __shfl_xor(hbits, 1, 64);
                    if ((hc & 1) == 0)
                        stg32(hb_new + cidx, (unsigned)hbits | ((unsigned)oth << 16));
                }
                __syncthreads();
                if (tid == 0) bump(CNT(k));
            } else {
                int pb = wg - 224;
                int mt = wave >> 2, q = wave & 3;
                int b = mt * 16 + rowm;
                int cg = q * 16 + rowm;
                const unsigned short* wtp = swA + cg * 776;
                const unsigned short* ep_ = et + b * 256;
                const unsigned short* shb = sh + b * 520;
#pragma unroll
                for (int kt = 0; kt < 24; ++kt) {
                    int ko = kt * 32 + ks * 8;
                    bf16x8 bf = frag_p(wtp + ko);
                    bf16x8 af = (kt < 16) ? frag_p(shb + ko) : frag_p(ep_ + ko - 512);
                    acc = __builtin_amdgcn_mfma_f32_16x16x32_bf16(af, bf, acc, 0, 0, 0);
                }
#pragma unroll
                for (int r2 = 0; r2 < 4; ++r2)
                    stgf(p2w + (mt * 16 + (lane >> 4) * 4 + r2) * 512 + pb * 64 + cg, acc[r2]);
                __syncthreads();
                if (tid == 0) bump(CNT(7));
            }
        }

        // ================= Phase B: attention partials (wg<224) =================
        if (wg < 224) {
            {
                unsigned* wp = nullptr; unsigned wthr = 0;
                if (tid == 0) { wp = CNT(kB); wthr = 32u * (t + 1); }
                else if (tid == 1) { wp = CNT(7); wthr = 8u * (t + 1); }
                else if (tid >= 2 && tid < 10 && t >= 1) {
                    wp = CNT(15 + tid - 2); wthr = 32u * (t - 1);   // WAR on partial buf
                }
                if (wp) spin_ge(wp, wthr);
            }
            __syncthreads();
            int mt = wave & 1, kq = wave >> 1;
            f32x4 acc = {0.f, 0.f, 0.f, 0.f};
            const unsigned short* wtp = WTp1 + (itB * 16 + rowm) * 512;
            const unsigned short* hp_ = hb_new + (kB * 32 + mt * 16 + rowm) * 512;
#pragma unroll
            for (int s4 = 0; s4 < 4; ++s4) {
                int ko = (kq * 4 + s4) * 32 + ks * 8;
                bf16x8 bf = frag_p(wtp + ko);
                bf16x8 af = frag_c(hp_ + ko);
                acc = __builtin_amdgcn_mfma_f32_16x16x32_bf16(af, bf, acc, 0, 0, 0);
            }
            ((f32x4*)smem)[wave * 64 + lane] = acc;
            __syncthreads();
            {
                int b2 = tid >> 4, i2 = tid & 15;
                int mt2 = b2 >> 4, rr = b2 & 15;
                int ln = ((rr & 12) << 2) | i2, rg = rr & 3;
                float val = 0.f;
#pragma unroll
                for (int q2 = 0; q2 < 4; ++q2)
                    val += smem[((q2 * 2 + mt2) * 64 + ln) * 4 + rg];
                val += ldcf(p2w + b2 * 512 + itB * 16 + i2);
                float sv = tanhf(val) * Us_w[itB * 16 + i2];
                sv += __shfl_xor(sv, 1, 64); sv += __shfl_xor(sv, 2, 64);
                sv += __shfl_xor(sv, 4, 64); sv += __shfl_xor(sv, 8, 64);
                if (i2 == 0) stgf(pbuf + (kB * 32 + itB) * 32 + b2, sv);
            }
            __syncthreads();
            if (tid == 0) bump(CNT(8 + kB));
        }

        // ================= Phase C: softmax + Rt + main gates + cell (256 WGs) ===
        {
            {
                unsigned* wp = nullptr; unsigned wthr = 0;
                if (tid < 7) { wp = CNT(8 + tid); wthr = 32u * (t + 1); }
                else if (tid < 15) { wp = CNT(15 + tid - 7); wthr = 32u * t; }
                if (wp) spin_ge(wp, wthr);
            }
            __syncthreads();
            int mh = wg >> 7, ntc = wg & 127;
            unsigned short* Rt = (unsigned short*)smem;
            float* sredc = smem + 4160;
            float* ssi = smem + 6208;
            float* sa  = smem + 6320;
            float* sg2 = smem + 6432;
            float* sred4 = smem + 6688;
            if (tid < 448) {
                int kq = tid % 7, bl = (tid / 7) % 16, part = tid / 112;
                const float* pp = pbuf + (size_t)kq * 1024 + (size_t)(part * 8) * 32
                                + mh * 16 + bl;
                float v0 = ldcf(pp);        float v1 = ldcf(pp + 32);
                float v2 = ldcf(pp + 64);   float v3 = ldcf(pp + 96);
                float v4 = ldcf(pp + 128);  float v5 = ldcf(pp + 160);
                float v6 = ldcf(pp + 192);  float v7 = ldcf(pp + 224);
                sred4[part * 112 + bl * 7 + kq] =
                    ((v0 + v1) + (v2 + v3)) + ((v4 + v5) + (v6 + v7));
            }
            __syncthreads();
            if (tid < 112)
                ssi[tid] = (sred4[tid] + sred4[112 + tid])
                         + (sred4[224 + tid] + sred4[336 + tid]);
            __syncthreads();
            if (tid < 16) {
                float mx = -1e30f;
                for (int kq = 0; kq < 7; ++kq) mx = fmaxf(mx, ssi[tid * 7 + kq]);
                float den = 0.f, e[7];
                for (int kq = 0; kq < 7; ++kq) { e[kq] = expf(ssi[tid * 7 + kq] - mx); den += e[kq]; }
                float rd = 1.f / den;
                for (int kq = 0; kq < 7; ++kq) sa[tid * 7 + kq] = e[kq] * rd;
            }
            __syncthreads();
            for (int i = tid; i < 4096; i += 512) {
                int bl = i >> 8, rp = i & 255;
                const unsigned short* hb0 = hb_new + (mh * 16 + bl) * 512 + 2 * rp;
                unsigned u0 = ldc32(hb0);
                unsigned u1 = ldc32(hb0 + 16384);
                unsigned u2 = ldc32(hb0 + 32768);
                unsigned u3 = ldc32(hb0 + 49152);
                unsigned u4 = ldc32(hb0 + 65536);
                unsigned u5 = ldc32(hb0 + 81920);
                unsigned u6 = ldc32(hb0 + 98304);
                const float* sab = sa + bl * 7;
                float a0 = 0.f, a1 = 0.f;
                a0 = fmaf(sab[0], b2f((unsigned short)u0), a0);
                a1 = fmaf(sab[0], b2f((unsigned short)(u0 >> 16)), a1);
                a0 = fmaf(sab[1], b2f((unsigned short)u1), a0);
                a1 = fmaf(sab[1], b2f((unsigned short)(u1 >> 16)), a1);
                a0 = fmaf(sab[2], b2f((unsigned short)u2), a0);
                a1 = fmaf(sab[2], b2f((unsigned short)(u2 >> 16)), a1);
                a0 = fmaf(sab[3], b2f((unsigned short)u3), a0);
                a1 = fmaf(sab[3], b2f((unsigned short)(u3 >> 16)), a1);
                a0 = fmaf(sab[4], b2f((unsigned short)u4), a0);
                a1 = fmaf(sab[4], b2f((unsigned short)(u4 >> 16)), a1);
                a0 = fmaf(sab[5], b2f((unsigned short)u5), a0);
                a1 = fmaf(sab[5], b2f((unsigned short)(u5 >> 16)), a1);
                a0 = fmaf(sab[6], b2f((unsigned short)u6), a0);
                a1 = fmaf(sab[6], b2f((unsigned short)(u6 >> 16)), a1);
                Rt[bl * 520 + 2 * rp]     = f2b(a0);
                Rt[bl * 520 + 2 * rp + 1] = f2b(a1);
            }
            __syncthreads();
            f32x4 acc = {0.f, 0.f, 0.f, 0.f};
            const unsigned short* wtp = WTc + (size_t)ntc * 20480 + rowm * 1280;
            int b = mh * 16 + rowm;
            const unsigned short* ep_ = et + b * 256;
            const unsigned short* hp_ = hm_old + b * 512;
            const unsigned short* rp_ = Rt + rowm * 520;
#pragma unroll
            for (int s5 = 0; s5 < 5; ++s5) {
                int kt = wave * 5 + s5;
                int ko = kt * 32 + ks * 8;
                bf16x8 bf = frag_p(wtp + ko);
                bf16x8 af;
                if (kt < 8) af = frag_p(ep_ + ko);
                else if (kt < 24) af = frag_c(hp_ + ko - 256);
                else af = frag_p(rp_ + ko - 768);
                acc = __builtin_amdgcn_mfma_f32_16x16x32_bf16(af, bf, acc, 0, 0, 0);
            }
            __syncthreads();
            ((f32x4*)sredc)[wave * 64 + lane] = acc;
            __syncthreads();
            if (tid < 256) {
                int rr = tid >> 4, c = tid & 15;
                int ln = ((rr & 12) << 2) | c, rg = rr & 3;
                float val = 0.f;
#pragma unroll
                for (int w2 = 0; w2 < 8; ++w2) val += sredc[(w2 * 64 + ln) * 4 + rg];
                sg2[rr * 16 + c] = val;
            }
            __syncthreads();
            if (tid < 64) {
                int bl = tid >> 2, j = tid & 3;
                int b2 = mh * 16 + bl;
                int colh = ntc * 4 + j;
                float gi = sg2[bl * 16 + 0  + j] + b_c[colh];
                float gf = sg2[bl * 16 + 4  + j] + b_c[512 + colh];
                float gg = sg2[bl * 16 + 8  + j] + b_c[1024 + colh];
                float go = sg2[bl * 16 + 12 + j] + b_c[1536 + colh];
                int cidx = b2 * 512 + colh;
                float cold = cmain[cidx];
                float cn = sigm(gf) * cold + sigm(gi) * tanhf(gg);
                float hn = sigm(go) * tanhf(cn);
                cmain[cidx] = cn;
                out[(size_t)b2 * 262144 + (size_t)t * 512 + colh] = hn;
                int hbits = (int)f2b(hn);
                int oth = __shfl_xor(hbits, 1, 64);
                if ((j & 1) == 0)
                    stg32(hm_new + cidx, (unsigned)hbits | ((unsigned)oth << 16));
                if (t == 511) stgf(hNf + cidx, hn);
            }
            __syncthreads();
            if (tid == 0) bump(CNT(15 + (wg >> 5)));
        }
    }

    // epilogue: wait all C(511) done, then copy hN
    if (tid < 8) spin_ge(CNT(15 + tid), 32u * 512u);
    __syncthreads();
    for (int i = wg * 512 + tid; i < 16384; i += 131072)
        out[8388608 + i] = ldcf(hNf + i);
}

extern "C" void kernel_launch(void* const* d_in, const int* in_sizes, int n_in,
                              void* d_out, int out_size, void* d_ws, size_t ws_size,
                              hipStream_t stream) {
    const int*   x      = (const int*)d_in[0];
    const int*   taskp  = (const int*)d_in[1];
    const float* embed  = (const float*)d_in[2];
    const float* Wx_t   = (const float*)d_in[3];
    const float* Wh_t   = (const float*)d_in[4];
    const float* b_t    = (const float*)d_in[5];
    const float* Ws_p1  = (const float*)d_in[6];
    const float* Ws_p2  = (const float*)d_in[7];
    const float* Us_w   = (const float*)d_in[8];
    const float* Wx_c   = (const float*)d_in[10];
    const float* Wh_c   = (const float*)d_in[11];
    const float* Wm_c   = (const float*)d_in[12];
    const float* b_c    = (const float*)d_in[13];
    float* out = (float*)d_out;

    unsigned short* us = (unsigned short*)d_ws;
    unsigned short* WTa   = us;                       // 11,010,048
    unsigned short* WTp2  = WTa   + 11010048;         //    393,216
    unsigned short* WTp1  = WTp2  + 393216;           //    262,144
    unsigned short* WTc   = WTp1  + 262144;           //  2,621,440
    unsigned short* embbf = WTc   + 2621440;          //  4,194,304
    unsigned short* hbf   = embbf + 4194304;          //    229,376
    unsigned short* hmbf  = hbf   + 229376;           //     32,768
    float* fb      = (float*)(hmbf + 32768);
    float* ctask   = fb;                              //    114,688
    float* cmain   = ctask + 114688;                  //     16,384
    float* p2w     = cmain + 16384;                   //     16,384
    float* partial = p2w   + 16384;                   //  2 x 7,168
    float* hNf     = partial + 14336;                 //     16,384
    unsigned* bar  = (unsigned*)(hNf + 16384);        //      8 KiB

    hipMemsetAsync(bar, 0, 8192, stream);

    void* args[] = { (void*)&x, (void*)&taskp, (void*)&embed,
                     (void*)&Wx_t, (void*)&Wh_t, (void*)&b_t,
                     (void*)&Ws_p1, (void*)&Ws_p2, (void*)&Us_w,
                     (void*)&Wx_c, (void*)&Wh_c, (void*)&Wm_c, (void*)&b_c,
                     (void*)&out,
                     (void*)&WTa, (void*)&WTp2, (void*)&WTp1, (void*)&WTc,
                     (void*)&embbf, (void*)&hbf, (void*)&hmbf,
                     (void*)&ctask, (void*)&cmain, (void*)&p2w, (void*)&partial,
                     (void*)&hNf, (void*)&bar };
    hipLaunchCooperativeKernel((void*)fused_all, dim3(256), dim3(512), args, 0, stream);
}

// Round 21
// 9752.327 us; speedup vs baseline: 1.7988x; 1.7988x over previous
//
#include <hip/hip_runtime.h>

#define S_ 512
#define SCOPE __HIP_MEMORY_SCOPE_AGENT

typedef short bf16x8 __attribute__((ext_vector_type(8)));
typedef float f32x4 __attribute__((ext_vector_type(4)));

__device__ __forceinline__ float sigm(float x) { return 1.f / (1.f + expf(-x)); }
__device__ __forceinline__ float b2f(unsigned short u) {
    return __builtin_bit_cast(float, (unsigned)u << 16);
}
__device__ __forceinline__ unsigned short f2b(float f) {
    unsigned x = __builtin_bit_cast(unsigned, f);
    return (unsigned short)((x + 0x7fffu + ((x >> 16) & 1u)) >> 16);
}
__device__ __forceinline__ float ldcf(const float* p) {
    return __hip_atomic_load(p, __ATOMIC_RELAXED, SCOPE);
}
__device__ __forceinline__ unsigned ldc32(const void* p) {
    return __hip_atomic_load((const unsigned*)p, __ATOMIC_RELAXED, SCOPE);
}
__device__ __forceinline__ unsigned long long ldc64(const void* p) {
    return __hip_atomic_load((const unsigned long long*)p, __ATOMIC_RELAXED, SCOPE);
}
__device__ __forceinline__ void stg32(void* p, unsigned v) {
    __hip_atomic_store((unsigned*)p, v, __ATOMIC_RELAXED, SCOPE);
}
__device__ __forceinline__ void stgf(float* p, float v) {
    __hip_atomic_store(p, v, __ATOMIC_RELAXED, SCOPE);
}
__device__ __forceinline__ bf16x8 frag_c(const unsigned short* p) {
    union { unsigned long long q[2]; bf16x8 v; } u;
    u.q[0] = ldc64(p); u.q[1] = ldc64(p + 4);
    return u.v;
}
__device__ __forceinline__ bf16x8 frag_p(const unsigned short* p) {
    return *(const bf16x8*)p;
}
__device__ __forceinline__ void spin_ge(unsigned* p, unsigned thr) {
    while (__hip_atomic_load(p, __ATOMIC_RELAXED, SCOPE) < thr)
        __builtin_amdgcn_s_sleep(1);
}

// one-time grid barrier (prologue only; validated round 9)
__device__ __forceinline__ void gbar(unsigned* bar, int tid, int wg, unsigned n) {
    __syncthreads();
    if (tid == 0) {
        int g = wg >> 5;
        unsigned* gcnt = bar + 64 + g * 32;
        unsigned* ggen = bar + 320 + g * 32;
        unsigned old = __hip_atomic_fetch_add(gcnt, 1u, __ATOMIC_RELAXED, SCOPE);
        if (old == n * 32u - 1u) {
            unsigned rold = __hip_atomic_fetch_add(bar, 1u, __ATOMIC_RELAXED, SCOPE);
            if (rold == n * 8u - 1u) {
                __hip_atomic_store(bar + 32, n, __ATOMIC_RELAXED, SCOPE);
            } else {
                while (__hip_atomic_load(bar + 32, __ATOMIC_RELAXED, SCOPE) < n)
                    __builtin_amdgcn_s_sleep(1);
            }
            __hip_atomic_store(ggen, n, __ATOMIC_RELAXED, SCOPE);
        } else {
            while (__hip_atomic_load(ggen, __ATOMIC_RELAXED, SCOPE) < n)
                __builtin_amdgcn_s_sleep(1);
        }
        asm volatile("" ::: "memory");
    }
    __syncthreads();
}

// flag-broadcast grid barrier: arrival = plain sc1 store (no RMW);
// wg0's 256 lanes poll the 256 flags in parallel; then one gen store.
// flags at bar+1024+wg*32 (128B spacing), gen at bar+576.
__device__ __forceinline__ void gbar2(unsigned* bar, int tid, int wg, unsigned bn) {
    __syncthreads();   // drains this WG's data stores (vmcnt 0) before flag store
    if (tid == 0) stg32(bar + 1024 + wg * 32, bn);
    if (wg == 0) {
        if (tid < 256) spin_ge(bar + 1024 + tid * 32, bn);
        __syncthreads();
        if (tid == 0) stg32(bar + 576, bn);
    } else {
        if (tid == 0) spin_ge(bar + 576, bn);
        __syncthreads();
    }
}

__global__ __launch_bounds__(512) void fused_all(
        const int* __restrict__ x, const int* __restrict__ taskp,
        const float* __restrict__ embed,
        const float* __restrict__ Wx_t, const float* __restrict__ Wh_t,
        const float* __restrict__ b_t,
        const float* __restrict__ Ws_p1, const float* __restrict__ Ws_p2,
        const float* __restrict__ Us_w,
        const float* __restrict__ Wx_c, const float* __restrict__ Wh_c,
        const float* __restrict__ Wm_c, const float* __restrict__ b_c,
        float* __restrict__ out,
        unsigned short* __restrict__ WTa,  unsigned short* __restrict__ WTp2,
        unsigned short* __restrict__ WTp1, unsigned short* __restrict__ WTc,
        unsigned short* __restrict__ embbf, unsigned short* __restrict__ hbf,
        unsigned short* __restrict__ hmbf,
        float* __restrict__ ctask, float* __restrict__ cmain,
        float* __restrict__ p2w, float* __restrict__ partial,
        float* __restrict__ hNf, unsigned* __restrict__ bar)
{
    __shared__ float smem[8320];
    __shared__ unsigned short swA[64 * 776];
    const int wg = blockIdx.x, tid = threadIdx.x;
    const int lane = tid & 63, wave = tid >> 6;
    const int rowm = lane & 15, ks = lane >> 4;
    const int task = taskp[0];
    unsigned bn = 0;

    // ================= prologue: zero state + bf16 transposed weight build ======
    for (int i = wg * 512 + tid; i < 114688; i += 131072) stg32((unsigned*)hbf + i, 0u);
    for (int i = wg * 512 + tid; i < 16384; i += 131072) stg32((unsigned*)hmbf + i, 0u);
    for (int i = wg * 512 + tid; i < 114688; i += 131072) stgf(ctask + i, 0.f);
    for (int i = wg * 512 + tid; i < 16384; i += 131072) stgf(cmain + i, 0.f);
    for (int i = wg * 512 + tid; i < 2097152; i += 131072) {
        int ts = i >> 12, b = (i >> 7) & 31, ep = i & 127;
        int tok = x[b * S_ + ts];
        const float* s = embed + (size_t)tok * 256 + 2 * ep;
        stg32((unsigned*)embbf + i, (unsigned)f2b(s[0]) | ((unsigned)f2b(s[1]) << 16));
    }
    for (int i = wg * 512 + tid; i < 5505024; i += 131072) {
        int s = i / 24576, r = i % 24576, kp = r >> 6, cg = r & 63;
        int k = s >> 5, nt = s & 31, kk = k + (k >= task);
        int col = ((cg >> 4) << 9) + nt * 16 + (cg & 15);
        int kr = kp * 2;
        const float* src = (kr < 256)
            ? Wx_t + (size_t)kk * 524288 + (size_t)kr * 2048 + col
            : Wh_t + (size_t)kk * 1048576 + (size_t)(kr - 256) * 2048 + col;
        stg32((unsigned*)WTa + (size_t)s * 24576 + cg * 384 + kp,
              (unsigned)f2b(src[0]) | ((unsigned)f2b(src[2048]) << 16));
    }
    for (int i = wg * 512 + tid; i < 196608; i += 131072) {
        int p = i / 24576, r = i % 24576, kp = r >> 6, cg = r & 63;
        int col = p * 64 + cg, kr = kp * 2;
        const float* src = Ws_p2 + (size_t)kr * 512 + col;
        stg32((unsigned*)WTp2 + p * 24576 + cg * 384 + kp,
              (unsigned)f2b(src[0]) | ((unsigned)f2b(src[512]) << 16));
    }
    for (int i = wg * 512 + tid; i < 131072; i += 131072) {
        const float* src = Ws_p1 + 2 * (size_t)i;
        stg32((unsigned*)WTp1 + i, (unsigned)f2b(src[0]) | ((unsigned)f2b(src[1]) << 16));
    }
    for (int i = wg * 512 + tid; i < 1310720; i += 131072) {
        int ntc = i / 10240, r = i % 10240, kp = r >> 4, cg = r & 15;
        int col = ((cg >> 2) << 9) + ntc * 4 + (cg & 3);
        int kr = kp * 2;
        const float* src = (kr < 256) ? Wx_c + (size_t)kr * 2048 + col
                         : (kr < 768) ? Wh_c + (size_t)(kr - 256) * 2048 + col
                                      : Wm_c + (size_t)(kr - 768) * 2048 + col;
        stg32((unsigned*)WTc + ntc * 10240 + cg * 640 + kp,
              (unsigned)f2b(src[0]) | ((unsigned)f2b(src[2048]) << 16));
    }
    gbar(bar, tid, wg, 1);

    if (wg < 232) {
        const unsigned* srcw = (const unsigned*)(wg < 224
            ? WTa + (size_t)wg * 49152 : WTp2 + (size_t)(wg - 224) * 49152);
        for (int i = tid; i < 24576; i += 512) {
            int cg = i / 384, kp = i % 384;
            ((unsigned*)(swA + cg * 776))[kp] = srcw[cg * 384 + kp];
        }
    }
    __syncthreads();

    const int xq = wg & 7, jq = wg >> 3;
    const int kB = jq >> 2, itB = xq + 8 * (jq & 3);

    for (int t = 0; t < S_; ++t) {
        const int old = t & 1, nw = old ^ 1;
        const unsigned short* hb_old = hbf + old * 114688;
        unsigned short* hb_new = hbf + nw * 114688;
        const unsigned short* hm_old = hmbf + old * 16384;
        unsigned short* hm_new = hmbf + nw * 16384;
        const unsigned short* et = embbf + (size_t)t * 8192;

        // ================= Phase A: task gates+cell (wg<224) + p2 (224..231) =====
        if (wg < 232) {
            const bool istask = wg < 224;
            unsigned short* sh = (unsigned short*)smem;   // [32][520]
            const unsigned short* hsrc = istask ? hb_old + (wg >> 5) * 16384 : hm_old;
            for (int i = tid; i < 4096; i += 512) {
                int row = i >> 7, c8 = i & 127;
                *(unsigned long long*)(sh + row * 520 + c8 * 4) =
                    ldc64(hsrc + row * 512 + c8 * 4);
            }
            __syncthreads();
            f32x4 acc = {0.f, 0.f, 0.f, 0.f};
            if (istask) {
                int k = wg >> 5, nt = wg & 31;
                int mt = wave >> 2, g = wave & 3;
                int b = mt * 16 + rowm;
                const unsigned short* wtp = swA + (g * 16 + rowm) * 776;
                const unsigned short* ep_ = et + b * 256;
                const unsigned short* shb = sh + b * 520;
#pragma unroll
                for (int kt = 0; kt < 24; ++kt) {
                    int ko = kt * 32 + ks * 8;
                    bf16x8 bf = frag_p(wtp + ko);
                    bf16x8 af = (kt < 8) ? frag_p(ep_ + ko) : frag_p(shb + ko - 256);
                    acc = __builtin_amdgcn_mfma_f32_16x16x32_bf16(af, bf, acc, 0, 0, 0);
                }
                __syncthreads();
                float* sg = smem;
#pragma unroll
                for (int r2 = 0; r2 < 4; ++r2)
                    sg[(mt * 16 + (lane >> 4) * 4 + r2) * 64 + g * 16 + rowm] = acc[r2];
                __syncthreads();
                {
                    int b2 = tid >> 4, hc = tid & 15;
                    int kk = k + (k >= task);
                    const float* bb = b_t + kk * 2048 + nt * 16 + hc;
                    float gi = sg[b2 * 64 + hc]      + bb[0];
                    float gf = sg[b2 * 64 + 16 + hc] + bb[512];
                    float gg = sg[b2 * 64 + 32 + hc] + bb[1024];
                    float go = sg[b2 * 64 + 48 + hc] + bb[1536];
                    int cidx = (k * 32 + b2) * 512 + nt * 16 + hc;
                    float cold = ctask[cidx];
                    float cn = sigm(gf) * cold + sigm(gi) * tanhf(gg);
                    float hn = sigm(go) * tanhf(cn);
                    ctask[cidx] = cn;
                    int hbits = (int)f2b(hn);
                    int oth = __shfl_xor(hbits, 1, 64);
                    if ((hc & 1) == 0)
                        stg32(hb_new + cidx, (unsigned)hbits | ((unsigned)oth << 16));
                }
            } else {
                int pb = wg - 224;
                int mt = wave >> 2, q = wave & 3;
                int b = mt * 16 + rowm;
                int cg = q * 16 + rowm;
                const unsigned short* wtp = swA + cg * 776;
                const unsigned short* ep_ = et + b * 256;
                const unsigned short* shb = sh + b * 520;
#pragma unroll
                for (int kt = 0; kt < 24; ++kt) {
                    int ko = kt * 32 + ks * 8;
                    bf16x8 bf = frag_p(wtp + ko);
                    bf16x8 af = (kt < 16) ? frag_p(shb + ko) : frag_p(ep_ + ko - 512);
                    acc = __builtin_amdgcn_mfma_f32_16x16x32_bf16(af, bf, acc, 0, 0, 0);
                }
#pragma unroll
                for (int r2 = 0; r2 < 4; ++r2)
                    stgf(p2w + (mt * 16 + (lane >> 4) * 4 + r2) * 512 + pb * 64 + cg, acc[r2]);
            }
        }
        gbar2(bar, tid, wg, ++bn);

        // ================= Phase B: attention partials (wg<224) =================
        if (wg < 224) {
            int mt = wave & 1, kq = wave >> 1;
            f32x4 acc = {0.f, 0.f, 0.f, 0.f};
            const unsigned short* wtp = WTp1 + (itB * 16 + rowm) * 512;
            const unsigned short* hp_ = hb_new + (kB * 32 + mt * 16 + rowm) * 512;
#pragma unroll
            for (int s4 = 0; s4 < 4; ++s4) {
                int ko = (kq * 4 + s4) * 32 + ks * 8;
                bf16x8 bf = frag_p(wtp + ko);
                bf16x8 af = frag_c(hp_ + ko);
                acc = __builtin_amdgcn_mfma_f32_16x16x32_bf16(af, bf, acc, 0, 0, 0);
            }
            ((f32x4*)smem)[wave * 64 + lane] = acc;
            __syncthreads();
            {
                int b2 = tid >> 4, i2 = tid & 15;
                int mt2 = b2 >> 4, rr = b2 & 15;
                int ln = ((rr & 12) << 2) | i2, rg = rr & 3;
                float val = 0.f;
#pragma unroll
                for (int q2 = 0; q2 < 4; ++q2)
                    val += smem[((q2 * 2 + mt2) * 64 + ln) * 4 + rg];
                val += ldcf(p2w + b2 * 512 + itB * 16 + i2);
                float sv = tanhf(val) * Us_w[itB * 16 + i2];
                sv += __shfl_xor(sv, 1, 64); sv += __shfl_xor(sv, 2, 64);
                sv += __shfl_xor(sv, 4, 64); sv += __shfl_xor(sv, 8, 64);
                if (i2 == 0) stgf(partial + (kB * 32 + itB) * 32 + b2, sv);
            }
        }
        gbar2(bar, tid, wg, ++bn);

        // ================= Phase C: softmax + Rt + main gates + cell (256 WGs) ===
        {
            int mh = wg >> 7, ntc = wg & 127;
            unsigned short* Rt = (unsigned short*)smem;
            float* sredc = smem + 4160;
            float* ssi = smem + 6208;
            float* sa  = smem + 6320;
            float* sg2 = smem + 6432;
            float* sred4 = smem + 6688;
            if (tid < 448) {
                int kq = tid % 7, bl = (tid / 7) % 16, part = tid / 112;
                const float* pp = partial + (size_t)kq * 1024 + (size_t)(part * 8) * 32
                                + mh * 16 + bl;
                float v0 = ldcf(pp);        float v1 = ldcf(pp + 32);
                float v2 = ldcf(pp + 64);   float v3 = ldcf(pp + 96);
                float v4 = ldcf(pp + 128);  float v5 = ldcf(pp + 160);
                float v6 = ldcf(pp + 192);  float v7 = ldcf(pp + 224);
                sred4[part * 112 + bl * 7 + kq] =
                    ((v0 + v1) + (v2 + v3)) + ((v4 + v5) + (v6 + v7));
            }
            __syncthreads();
            if (tid < 112)
                ssi[tid] = (sred4[tid] + sred4[112 + tid])
                         + (sred4[224 + tid] + sred4[336 + tid]);
            __syncthreads();
            if (tid < 16) {
                float mx = -1e30f;
                for (int kq = 0; kq < 7; ++kq) mx = fmaxf(mx, ssi[tid * 7 + kq]);
                float den = 0.f, e[7];
                for (int kq = 0; kq < 7; ++kq) { e[kq] = expf(ssi[tid * 7 + kq] - mx); den += e[kq]; }
                float rd = 1.f / den;
                for (int kq = 0; kq < 7; ++kq) sa[tid * 7 + kq] = e[kq] * rd;
            }
            __syncthreads();
            for (int i = tid; i < 4096; i += 512) {
                int bl = i >> 8, rp = i & 255;
                const unsigned short* hb0 = hb_new + (mh * 16 + bl) * 512 + 2 * rp;
                unsigned u0 = ldc32(hb0);
                unsigned u1 = ldc32(hb0 + 16384);
                unsigned u2 = ldc32(hb0 + 32768);
                unsigned u3 = ldc32(hb0 + 49152);
                unsigned u4 = ldc32(hb0 + 65536);
                unsigned u5 = ldc32(hb0 + 81920);
                unsigned u6 = ldc32(hb0 + 98304);
                const float* sab = sa + bl * 7;
                float a0 = 0.f, a1 = 0.f;
                a0 = fmaf(sab[0], b2f((unsigned short)u0), a0);
                a1 = fmaf(sab[0], b2f((unsigned short)(u0 >> 16)), a1);
                a0 = fmaf(sab[1], b2f((unsigned short)u1), a0);
                a1 = fmaf(sab[1], b2f((unsigned short)(u1 >> 16)), a1);
                a0 = fmaf(sab[2], b2f((unsigned short)u2), a0);
                a1 = fmaf(sab[2], b2f((unsigned short)(u2 >> 16)), a1);
                a0 = fmaf(sab[3], b2f((unsigned short)u3), a0);
                a1 = fmaf(sab[3], b2f((unsigned short)(u3 >> 16)), a1);
                a0 = fmaf(sab[4], b2f((unsigned short)u4), a0);
                a1 = fmaf(sab[4], b2f((unsigned short)(u4 >> 16)), a1);
                a0 = fmaf(sab[5], b2f((unsigned short)u5), a0);
                a1 = fmaf(sab[5], b2f((unsigned short)(u5 >> 16)), a1);
                a0 = fmaf(sab[6], b2f((unsigned short)u6), a0);
                a1 = fmaf(sab[6], b2f((unsigned short)(u6 >> 16)), a1);
                Rt[bl * 520 + 2 * rp]     = f2b(a0);
                Rt[bl * 520 + 2 * rp + 1] = f2b(a1);
            }
            __syncthreads();
            f32x4 acc = {0.f, 0.f, 0.f, 0.f};
            const unsigned short* wtp = WTc + (size_t)ntc * 20480 + rowm * 1280;
            int b = mh * 16 + rowm;
            const unsigned short* ep_ = et + b * 256;
            const unsigned short* hp_ = hm_old + b * 512;
            const unsigned short* rp_ = Rt + rowm * 520;
#pragma unroll
            for (int s5 = 0; s5 < 5; ++s5) {
                int kt = wave * 5 + s5;
                int ko = kt * 32 + ks * 8;
                bf16x8 bf = frag_p(wtp + ko);
                bf16x8 af;
                if (kt < 8) af = frag_p(ep_ + ko);
                else if (kt < 24) af = frag_c(hp_ + ko - 256);
                else af = frag_p(rp_ + ko - 768);
                acc = __builtin_amdgcn_mfma_f32_16x16x32_bf16(af, bf, acc, 0, 0, 0);
            }
            __syncthreads();
            ((f32x4*)sredc)[wave * 64 + lane] = acc;
            __syncthreads();
            if (tid < 256) {
                int rr = tid >> 4, c = tid & 15;
                int ln = ((rr & 12) << 2) | c, rg = rr & 3;
                float val = 0.f;
#pragma unroll
                for (int w2 = 0; w2 < 8; ++w2) val += sredc[(w2 * 64 + ln) * 4 + rg];
                sg2[rr * 16 + c] = val;
            }
            __syncthreads();
            if (tid < 64) {
                int bl = tid >> 2, j = tid & 3;
                int b2 = mh * 16 + bl;
                int colh = ntc * 4 + j;
                float gi = sg2[bl * 16 + 0  + j] + b_c[colh];
                float gf = sg2[bl * 16 + 4  + j] + b_c[512 + colh];
                float gg = sg2[bl * 16 + 8  + j] + b_c[1024 + colh];
                float go = sg2[bl * 16 + 12 + j] + b_c[1536 + colh];
                int cidx = b2 * 512 + colh;
                float cold = cmain[cidx];
                float cn = sigm(gf) * cold + sigm(gi) * tanhf(gg);
                float hn = sigm(go) * tanhf(cn);
                cmain[cidx] = cn;
                out[(size_t)b2 * 262144 + (size_t)t * 512 + colh] = hn;
                int hbits = (int)f2b(hn);
                int oth = __shfl_xor(hbits, 1, 64);
                if ((j & 1) == 0)
                    stg32(hm_new + cidx, (unsigned)hbits | ((unsigned)oth << 16));
                if (t == 511) stgf(hNf + cidx, hn);
            }
        }
        gbar2(bar, tid, wg, ++bn);
    }

    for (int i = wg * 512 + tid; i < 16384; i += 131072)
        out[8388608 + i] = ldcf(hNf + i);
}

extern "C" void kernel_launch(void* const* d_in, const int* in_sizes, int n_in,
                              void* d_out, int out_size, void* d_ws, size_t ws_size,
                              hipStream_t stream) {
    const int*   x      = (const int*)d_in[0];
    const int*   taskp  = (const int*)d_in[1];
    const float* embed  = (const float*)d_in[2];
    const float* Wx_t   = (const float*)d_in[3];
    const float* Wh_t   = (const float*)d_in[4];
    const float* b_t    = (const float*)d_in[5];
    const float* Ws_p1  = (const float*)d_in[6];
    const float* Ws_p2  = (const float*)d_in[7];
    const float* Us_w   = (const float*)d_in[8];
    const float* Wx_c   = (const float*)d_in[10];
    const float* Wh_c   = (const float*)d_in[11];
    const float* Wm_c   = (const float*)d_in[12];
    const float* b_c    = (const float*)d_in[13];
    float* out = (float*)d_out;

    unsigned short* us = (unsigned short*)d_ws;
    unsigned short* WTa   = us;                       // 11,010,048
    unsigned short* WTp2  = WTa   + 11010048;         //    393,216
    unsigned short* WTp1  = WTp2  + 393216;           //    262,144
    unsigned short* WTc   = WTp1  + 262144;           //  2,621,440
    unsigned short* embbf = WTc   + 2621440;          //  4,194,304
    unsigned short* hbf   = embbf + 4194304;          //    229,376
    unsigned short* hmbf  = hbf   + 229376;           //     32,768
    float* fb      = (float*)(hmbf + 32768);
    float* ctask   = fb;                              //    114,688
    float* cmain   = ctask + 114688;                  //     16,384
    float* p2w     = cmain + 16384;                   //     16,384
    float* partial = p2w   + 16384;                   //      7,168
    float* hNf     = partial + 7168;                  //     16,384
    unsigned* bar  = (unsigned*)(hNf + 16384);        //  40 KiB (flags + gen + tree)

    hipMemsetAsync(bar, 0, 40960, stream);

    void* args[] = { (void*)&x, (void*)&taskp, (void*)&embed,
                     (void*)&Wx_t, (void*)&Wh_t, (void*)&b_t,
                     (void*)&Ws_p1, (void*)&Ws_p2, (void*)&Us_w,
                     (void*)&Wx_c, (void*)&Wh_c, (void*)&Wm_c, (void*)&b_c,
                     (void*)&out,
                     (void*)&WTa, (void*)&WTp2, (void*)&WTp1, (void*)&WTc,
                     (void*)&embbf, (void*)&hbf, (void*)&hmbf,
                     (void*)&ctask, (void*)&cmain, (void*)&p2w, (void*)&partial,
                     (void*)&hNf, (void*)&bar };
    hipLaunchCooperativeKernel((void*)fused_all, dim3(256), dim3(512), args, 0, stream);
}

// Round 22
// 9449.344 us; speedup vs baseline: 1.8565x; 1.0321x over previous
//
#include <hip/hip_runtime.h>

#define S_ 512
#define SCOPE __HIP_MEMORY_SCOPE_AGENT

typedef short bf16x8 __attribute__((ext_vector_type(8)));
typedef float f32x4 __attribute__((ext_vector_type(4)));

__device__ __forceinline__ float sigm(float x) { return 1.f / (1.f + expf(-x)); }
__device__ __forceinline__ float b2f(unsigned short u) {
    return __builtin_bit_cast(float, (unsigned)u << 16);
}
__device__ __forceinline__ unsigned short f2b(float f) {
    unsigned x = __builtin_bit_cast(unsigned, f);
    return (unsigned short)((x + 0x7fffu + ((x >> 16) & 1u)) >> 16);
}
__device__ __forceinline__ float ldcf(const float* p) {
    return __hip_atomic_load(p, __ATOMIC_RELAXED, SCOPE);
}
__device__ __forceinline__ unsigned ldc32(const void* p) {
    return __hip_atomic_load((const unsigned*)p, __ATOMIC_RELAXED, SCOPE);
}
__device__ __forceinline__ unsigned long long ldc64(const void* p) {
    return __hip_atomic_load((const unsigned long long*)p, __ATOMIC_RELAXED, SCOPE);
}
__device__ __forceinline__ void stg32(void* p, unsigned v) {
    __hip_atomic_store((unsigned*)p, v, __ATOMIC_RELAXED, SCOPE);
}
__device__ __forceinline__ void stgf(float* p, float v) {
    __hip_atomic_store(p, v, __ATOMIC_RELAXED, SCOPE);
}
__device__ __forceinline__ bf16x8 frag_c(const unsigned short* p) {
    union { unsigned long long q[2]; bf16x8 v; } u;
    u.q[0] = ldc64(p); u.q[1] = ldc64(p + 4);
    return u.v;
}
__device__ __forceinline__ bf16x8 frag_p(const unsigned short* p) {
    return *(const bf16x8*)p;
}
__device__ __forceinline__ void spin_ge(unsigned* p, unsigned thr) {
    while (__hip_atomic_load(p, __ATOMIC_RELAXED, SCOPE) < thr)
        __builtin_amdgcn_s_sleep(1);
}

// one-time grid barrier (prologue only; validated round 9)
__device__ __forceinline__ void gbar(unsigned* bar, int tid, int wg, unsigned n) {
    __syncthreads();
    if (tid == 0) {
        int g = wg >> 5;
        unsigned* gcnt = bar + 64 + g * 32;
        unsigned* ggen = bar + 320 + g * 32;
        unsigned old = __hip_atomic_fetch_add(gcnt, 1u, __ATOMIC_RELAXED, SCOPE);
        if (old == n * 32u - 1u) {
            unsigned rold = __hip_atomic_fetch_add(bar, 1u, __ATOMIC_RELAXED, SCOPE);
            if (rold == n * 8u - 1u) {
                __hip_atomic_store(bar + 32, n, __ATOMIC_RELAXED, SCOPE);
            } else {
                while (__hip_atomic_load(bar + 32, __ATOMIC_RELAXED, SCOPE) < n)
                    __builtin_amdgcn_s_sleep(1);
            }
            __hip_atomic_store(ggen, n, __ATOMIC_RELAXED, SCOPE);
        } else {
            while (__hip_atomic_load(ggen, __ATOMIC_RELAXED, SCOPE) < n)
                __builtin_amdgcn_s_sleep(1);
        }
        asm volatile("" ::: "memory");
    }
    __syncthreads();
}

// flag-broadcast barrier with optional wait-skip (coordinator = wg 255,
// idle in phases A and B). Flags monotonic -> early re-arrival is safe.
__device__ __forceinline__ void gbar3(unsigned* bar, int tid, int wg, unsigned bn,
                                      bool wait) {
    __syncthreads();   // drains this WG's data stores before the flag store
    if (tid == 0) stg32(bar + 1024 + wg * 32, bn);
    if (wg == 255) {
        if (tid < 256) spin_ge(bar + 1024 + tid * 32, bn);
        __syncthreads();
        if (tid == 0) stg32(bar + 576, bn);
    } else if (wait) {
        if (tid == 0) spin_ge(bar + 576, bn);
        __syncthreads();
    }
}

__global__ __launch_bounds__(512) void fused_all(
        const int* __restrict__ x, const int* __restrict__ taskp,
        const float* __restrict__ embed,
        const float* __restrict__ Wx_t, const float* __restrict__ Wh_t,
        const float* __restrict__ b_t,
        const float* __restrict__ Ws_p1, const float* __restrict__ Ws_p2,
        const float* __restrict__ Us_w,
        const float* __restrict__ Wx_c, const float* __restrict__ Wh_c,
        const float* __restrict__ Wm_c, const float* __restrict__ b_c,
        float* __restrict__ out,
        unsigned short* __restrict__ WTa,  unsigned short* __restrict__ WTp2,
        unsigned short* __restrict__ WTp1, unsigned short* __restrict__ WTc,
        unsigned short* __restrict__ embbf, unsigned short* __restrict__ hbf,
        unsigned short* __restrict__ hmbf,
        float* __restrict__ ctask, float* __restrict__ cmain,
        float* __restrict__ p2w, float* __restrict__ partial,
        float* __restrict__ hNf, unsigned* __restrict__ bar)
{
    __shared__ float smem[9344];                 // 37,376 B
    __shared__ unsigned short swA[64 * 776];     // 99,328 B
    const int wg = blockIdx.x, tid = threadIdx.x;
    const int lane = tid & 63, wave = tid >> 6;
    const int rowm = lane & 15, ks = lane >> 4;
    const int task = taskp[0];
    unsigned bn = 0;

    // ================= prologue: zero state + bf16 transposed weight build ======
    for (int i = wg * 512 + tid; i < 114688; i += 131072) stg32((unsigned*)hbf + i, 0u);
    for (int i = wg * 512 + tid; i < 16384; i += 131072) stg32((unsigned*)hmbf + i, 0u);
    for (int i = wg * 512 + tid; i < 114688; i += 131072) stgf(ctask + i, 0.f);
    for (int i = wg * 512 + tid; i < 16384; i += 131072) stgf(cmain + i, 0.f);
    for (int i = wg * 512 + tid; i < 2097152; i += 131072) {
        int ts = i >> 12, b = (i >> 7) & 31, ep = i & 127;
        int tok = x[b * S_ + ts];
        const float* s = embed + (size_t)tok * 256 + 2 * ep;
        stg32((unsigned*)embbf + i, (unsigned)f2b(s[0]) | ((unsigned)f2b(s[1]) << 16));
    }
    for (int i = wg * 512 + tid; i < 5505024; i += 131072) {
        int s = i / 24576, r = i % 24576, kp = r >> 6, cg = r & 63;
        int k = s >> 5, nt = s & 31, kk = k + (k >= task);
        int col = ((cg >> 4) << 9) + nt * 16 + (cg & 15);
        int kr = kp * 2;
        const float* src = (kr < 256)
            ? Wx_t + (size_t)kk * 524288 + (size_t)kr * 2048 + col
            : Wh_t + (size_t)kk * 1048576 + (size_t)(kr - 256) * 2048 + col;
        stg32((unsigned*)WTa + (size_t)s * 24576 + cg * 384 + kp,
              (unsigned)f2b(src[0]) | ((unsigned)f2b(src[2048]) << 16));
    }
    for (int i = wg * 512 + tid; i < 196608; i += 131072) {
        int p = i / 24576, r = i % 24576, kp = r >> 6, cg = r & 63;
        int col = p * 64 + cg, kr = kp * 2;
        const float* src = Ws_p2 + (size_t)kr * 512 + col;
        stg32((unsigned*)WTp2 + p * 24576 + cg * 384 + kp,
              (unsigned)f2b(src[0]) | ((unsigned)f2b(src[512]) << 16));
    }
    for (int i = wg * 512 + tid; i < 131072; i += 131072) {
        const float* src = Ws_p1 + 2 * (size_t)i;
        stg32((unsigned*)WTp1 + i, (unsigned)f2b(src[0]) | ((unsigned)f2b(src[1]) << 16));
    }
    for (int i = wg * 512 + tid; i < 1310720; i += 131072) {
        int ntc = i / 10240, r = i % 10240, kp = r >> 4, cg = r & 15;
        int col = ((cg >> 2) << 9) + ntc * 4 + (cg & 3);
        int kr = kp * 2;
        const float* src = (kr < 256) ? Wx_c + (size_t)kr * 2048 + col
                         : (kr < 768) ? Wh_c + (size_t)(kr - 256) * 2048 + col
                                      : Wm_c + (size_t)(kr - 768) * 2048 + col;
        stg32((unsigned*)WTc + ntc * 10240 + cg * 640 + kp,
              (unsigned)f2b(src[0]) | ((unsigned)f2b(src[2048]) << 16));
    }
    gbar(bar, tid, wg, 1);

    if (wg < 232) {
        const unsigned* srcw = (const unsigned*)(wg < 224
            ? WTa + (size_t)wg * 49152 : WTp2 + (size_t)(wg - 224) * 49152);
        for (int i = tid; i < 24576; i += 512) {
            int cg = i / 384, kp = i % 384;
            ((unsigned*)(swA + cg * 776))[kp] = srcw[cg * 384 + kp];
        }
    }
    __syncthreads();

    const int xq = wg & 7, jq = wg >> 3;
    const int kB = jq >> 2, itB = xq + 8 * (jq & 3);

    for (int t = 0; t < S_; ++t) {
        const int old = t & 1, nw = old ^ 1;
        const unsigned short* hb_old = hbf + old * 114688;
        unsigned short* hb_new = hbf + nw * 114688;
        const unsigned short* hm_old = hmbf + old * 16384;
        unsigned short* hm_new = hmbf + nw * 16384;
        const unsigned short* et = embbf + (size_t)t * 8192;

        // ================= Phase A: task gates+cell (wg<224) + p2 (224..231) =====
        if (wg < 232) {
            const bool istask = wg < 224;
            unsigned short* sh = (unsigned short*)smem;   // [32][520]
            const unsigned short* hsrc = istask ? hb_old + (wg >> 5) * 16384 : hm_old;
            const int mt = wave >> 2, g = wave & 3;
            const int bA = mt * 16 + rowm;
            const unsigned short* ep_ = et + bA * 256;
            for (int i = tid; i < 4096; i += 512) {       // stage 32x512 h-slice
                int row = i >> 7, c8 = i & 127;
                *(unsigned long long*)(sh + row * 520 + c8 * 4) =
                    ldc64(hsrc + row * 512 + c8 * 4);
            }
            bf16x8 ee[8];                                 // emb frags: latency merges
#pragma unroll
            for (int j = 0; j < 8; ++j) ee[j] = frag_p(ep_ + j * 32 + ks * 8);
            __syncthreads();
            f32x4 acc = {0.f, 0.f, 0.f, 0.f};
            if (istask) {
                int k = wg >> 5, nt = wg & 31;
                const unsigned short* wtp = swA + (g * 16 + rowm) * 776;
                const unsigned short* shb = sh + bA * 520;
#pragma unroll
                for (int kt = 0; kt < 24; ++kt) {
                    int ko = kt * 32 + ks * 8;
                    bf16x8 bf = frag_p(wtp + ko);
                    bf16x8 af = (kt < 8) ? ee[kt < 8 ? kt : 0]
                                         : frag_p(shb + ko - 256);
                    acc = __builtin_amdgcn_mfma_f32_16x16x32_bf16(af, bf, acc, 0, 0, 0);
                }
                __syncthreads();
                float* sg = smem;
#pragma unroll
                for (int r2 = 0; r2 < 4; ++r2)
                    sg[(mt * 16 + (lane >> 4) * 4 + r2) * 64 + g * 16 + rowm] = acc[r2];
                __syncthreads();
                {
                    int b2 = tid >> 4, hc = tid & 15;
                    int kk = k + (k >= task);
                    const float* bb = b_t + kk * 2048 + nt * 16 + hc;
                    float gi = sg[b2 * 64 + hc]      + bb[0];
                    float gf = sg[b2 * 64 + 16 + hc] + bb[512];
                    float gg = sg[b2 * 64 + 32 + hc] + bb[1024];
                    float go = sg[b2 * 64 + 48 + hc] + bb[1536];
                    int cidx = (k * 32 + b2) * 512 + nt * 16 + hc;
                    float cold = ctask[cidx];
                    float cn = sigm(gf) * cold + sigm(gi) * tanhf(gg);
                    float hn = sigm(go) * tanhf(cn);
                    ctask[cidx] = cn;
                    int hbits = (int)f2b(hn);
                    int oth = __shfl_xor(hbits, 1, 64);
                    if ((hc & 1) == 0)
                        stg32(hb_new + cidx, (unsigned)hbits | ((unsigned)oth << 16));
                }
            } else {
                int pb = wg - 224;
                int cg = g * 16 + rowm;
                const unsigned short* wtp = swA + cg * 776;
                const unsigned short* shb = sh + bA * 520;
#pragma unroll
                for (int kt = 0; kt < 24; ++kt) {
                    int ko = kt * 32 + ks * 8;
                    bf16x8 bf = frag_p(wtp + ko);
                    bf16x8 af = (kt < 16) ? frag_p(shb + ko)
                                          : ee[kt >= 16 ? kt - 16 : 0];
                    acc = __builtin_amdgcn_mfma_f32_16x16x32_bf16(af, bf, acc, 0, 0, 0);
                }
#pragma unroll
                for (int r2 = 0; r2 < 4; ++r2)
                    stgf(p2w + (mt * 16 + (lane >> 4) * 4 + r2) * 512 + pb * 64 + cg, acc[r2]);
            }
        }
        gbar3(bar, tid, wg, ++bn, true);

        // ================= Phase B: attention partials (wg<224) =================
        if (wg < 224) {
            int mt = wave & 1, kq = wave >> 1;
            f32x4 acc = {0.f, 0.f, 0.f, 0.f};
            const unsigned short* wtp = WTp1 + (itB * 16 + rowm) * 512;
            const unsigned short* hp_ = hb_new + (kB * 32 + mt * 16 + rowm) * 512;
#pragma unroll
            for (int s4 = 0; s4 < 4; ++s4) {
                int ko = (kq * 4 + s4) * 32 + ks * 8;
                bf16x8 bf = frag_p(wtp + ko);
                bf16x8 af = frag_c(hp_ + ko);
                acc = __builtin_amdgcn_mfma_f32_16x16x32_bf16(af, bf, acc, 0, 0, 0);
            }
            ((f32x4*)smem)[wave * 64 + lane] = acc;
            __syncthreads();
            {
                int b2 = tid >> 4, i2 = tid & 15;
                int mt2 = b2 >> 4, rr = b2 & 15;
                int ln = ((rr & 12) << 2) | i2, rg = rr & 3;
                float val = 0.f;
#pragma unroll
                for (int q2 = 0; q2 < 4; ++q2)
                    val += smem[((q2 * 2 + mt2) * 64 + ln) * 4 + rg];
                val += ldcf(p2w + b2 * 512 + itB * 16 + i2);
                float sv = tanhf(val) * Us_w[itB * 16 + i2];
                sv += __shfl_xor(sv, 1, 64); sv += __shfl_xor(sv, 2, 64);
                sv += __shfl_xor(sv, 4, 64); sv += __shfl_xor(sv, 8, 64);
                if (i2 == 0) stgf(partial + (kB * 32 + itB) * 32 + b2, sv);
            }
        }
        gbar3(bar, tid, wg, ++bn, true);

        // ================= Phase C: softmax + Rt + main gates + cell (256 WGs) ===
        {
            int mh = wg >> 7, ntc = wg & 127;
            unsigned short* Rt = (unsigned short*)(smem + 4160);  // [16][520]
            float* sredc = smem;                                  // overlays (dead sh)
            float* ssi = smem + 8320;
            float* sa  = smem + 8432;
            float* sg2 = smem + 8544;
            float* sred4 = smem + 8800;
            // issue Rt source loads (56/thread, registers) + ssi loads concurrently
            unsigned uu[8][7];
#pragma unroll
            for (int j = 0; j < 8; ++j) {
                int i = tid + 512 * j;
                int bl = i >> 8, rp = i & 255;
                const unsigned short* hb0 = hb_new + (mh * 16 + bl) * 512 + 2 * rp;
#pragma unroll
                for (int kq = 0; kq < 7; ++kq)
                    uu[j][kq] = ldc32(hb0 + kq * 16384);
            }
            if (tid < 448) {
                int kq = tid % 7, bl = (tid / 7) % 16, part = tid / 112;
                const float* pp = partial + (size_t)kq * 1024 + (size_t)(part * 8) * 32
                                + mh * 16 + bl;
                float v0 = ldcf(pp);        float v1 = ldcf(pp + 32);
                float v2 = ldcf(pp + 64);   float v3 = ldcf(pp + 96);
                float v4 = ldcf(pp + 128);  float v5 = ldcf(pp + 160);
                float v6 = ldcf(pp + 192);  float v7 = ldcf(pp + 224);
                sred4[part * 112 + bl * 7 + kq] =
                    ((v0 + v1) + (v2 + v3)) + ((v4 + v5) + (v6 + v7));
            }
            __syncthreads();
            if (tid < 112)
                ssi[tid] = (sred4[tid] + sred4[112 + tid])
                         + (sred4[224 + tid] + sred4[336 + tid]);
            __syncthreads();
            if (tid < 16) {
                float mx = -1e30f;
                for (int kq = 0; kq < 7; ++kq) mx = fmaxf(mx, ssi[tid * 7 + kq]);
                float den = 0.f, e[7];
                for (int kq = 0; kq < 7; ++kq) { e[kq] = expf(ssi[tid * 7 + kq] - mx); den += e[kq]; }
                float rd = 1.f / den;
                for (int kq = 0; kq < 7; ++kq) sa[tid * 7 + kq] = e[kq] * rd;
            }
            __syncthreads();
#pragma unroll
            for (int j = 0; j < 8; ++j) {     // Rt FMA from preloaded registers
                int i = tid + 512 * j;
                int bl = i >> 8, rp = i & 255;
                const float* sab = sa + bl * 7;
                float a0 = 0.f, a1 = 0.f;
#pragma unroll
                for (int kq = 0; kq < 7; ++kq) {
                    unsigned u = uu[j][kq];
                    a0 = fmaf(sab[kq], b2f((unsigned short)u), a0);
                    a1 = fmaf(sab[kq], b2f((unsigned short)(u >> 16)), a1);
                }
                Rt[bl * 520 + 2 * rp]     = f2b(a0);
                Rt[bl * 520 + 2 * rp + 1] = f2b(a1);
            }
            __syncthreads();
            f32x4 acc = {0.f, 0.f, 0.f, 0.f};
            const unsigned short* wtp = WTc + (size_t)ntc * 20480 + rowm * 1280;
            int b = mh * 16 + rowm;
            const unsigned short* ep_ = et + b * 256;
            const unsigned short* hp_ = hm_old + b * 512;
            const unsigned short* rp_ = Rt + rowm * 520;
#pragma unroll
            for (int s5 = 0; s5 < 5; ++s5) {
                int kt = wave * 5 + s5;
                int ko = kt * 32 + ks * 8;
                bf16x8 bf = frag_p(wtp + ko);
                bf16x8 af;
                if (kt < 8) af = frag_p(ep_ + ko);
                else if (kt < 24) af = frag_c(hp_ + ko - 256);
                else af = frag_p(rp_ + ko - 768);
                acc = __builtin_amdgcn_mfma_f32_16x16x32_bf16(af, bf, acc, 0, 0, 0);
            }
            __syncthreads();          // Rt reads done before sredc overlays smem base
            ((f32x4*)sredc)[wave * 64 + lane] = acc;
            __syncthreads();
            if (tid < 256) {
                int rr = tid >> 4, c = tid & 15;
                int ln = ((rr & 12) << 2) | c, rg = rr & 3;
                float val = 0.f;
#pragma unroll
                for (int w2 = 0; w2 < 8; ++w2) val += sredc[(w2 * 64 + ln) * 4 + rg];
                sg2[rr * 16 + c] = val;
            }
            __syncthreads();
            if (tid < 64) {
                int bl = tid >> 2, j = tid & 3;
                int b2 = mh * 16 + bl;
                int colh = ntc * 4 + j;
                float gi = sg2[bl * 16 + 0  + j] + b_c[colh];
                float gf = sg2[bl * 16 + 4  + j] + b_c[512 + colh];
                float gg = sg2[bl * 16 + 8  + j] + b_c[1024 + colh];
                float go = sg2[bl * 16 + 12 + j] + b_c[1536 + colh];
                int cidx = b2 * 512 + colh;
                float cold = cmain[cidx];
                float cn = sigm(gf) * cold + sigm(gi) * tanhf(gg);
                float hn = sigm(go) * tanhf(cn);
                cmain[cidx] = cn;
                out[(size_t)b2 * 262144 + (size_t)t * 512 + colh] = hn;
                int hbits = (int)f2b(hn);
                int oth = __shfl_xor(hbits, 1, 64);
                if ((j & 1) == 0)
                    stg32(hm_new + cidx, (unsigned)hbits | ((unsigned)oth << 16));
                if (t == 511) stgf(hNf + cidx, hn);
            }
        }
        // task WGs (wg<224) skip the wait: A-task(t+1) needs nothing from C(t)
        gbar3(bar, tid, wg, ++bn, wg >= 224);
    }

    // epilogue: ensure all C(511) done (gen == 1536), then copy hN
    if (tid == 0) spin_ge(bar + 576, 1536u);
    __syncthreads();
    for (int i = wg * 512 + tid; i < 16384; i += 131072)
        out[8388608 + i] = ldcf(hNf + i);
}

extern "C" void kernel_launch(void* const* d_in, const int* in_sizes, int n_in,
                              void* d_out, int out_size, void* d_ws, size_t ws_size,
                              hipStream_t stream) {
    const int*   x      = (const int*)d_in[0];
    const int*   taskp  = (const int*)d_in[1];
    const float* embed  = (const float*)d_in[2];
    const float* Wx_t   = (const float*)d_in[3];
    const float* Wh_t   = (const float*)d_in[4];
    const float* b_t    = (const float*)d_in[5];
    const float* Ws_p1  = (const float*)d_in[6];
    const float* Ws_p2  = (const float*)d_in[7];
    const float* Us_w   = (const float*)d_in[8];
    const float* Wx_c   = (const float*)d_in[10];
    const float* Wh_c   = (const float*)d_in[11];
    const float* Wm_c   = (const float*)d_in[12];
    const float* b_c    = (const float*)d_in[13];
    float* out = (float*)d_out;

    unsigned short* us = (unsigned short*)d_ws;
    unsigned short* WTa   = us;                       // 11,010,048
    unsigned short* WTp2  = WTa   + 11010048;         //    393,216
    unsigned short* WTp1  = WTp2  + 393216;           //    262,144
    unsigned short* WTc   = WTp1  + 262144;           //  2,621,440
    unsigned short* embbf = WTc   + 2621440;          //  4,194,304
    unsigned short* hbf   = embbf + 4194304;          //    229,376
    unsigned short* hmbf  = hbf   + 229376;           //     32,768
    float* fb      = (float*)(hmbf + 32768);
    float* ctask   = fb;                              //    114,688
    float* cmain   = ctask + 114688;                  //     16,384
    float* p2w     = cmain + 16384;                   //     16,384
    float* partial = p2w   + 16384;                   //      7,168
    float* hNf     = partial + 7168;                  //     16,384
    unsigned* bar  = (unsigned*)(hNf + 16384);        //  40 KiB (flags + gen + tree)

    hipMemsetAsync(bar, 0, 40960, stream);

    void* args[] = { (void*)&x, (void*)&taskp, (void*)&embed,
                     (void*)&Wx_t, (void*)&Wh_t, (void*)&b_t,
                     (void*)&Ws_p1, (void*)&Ws_p2, (void*)&Us_w,
                     (void*)&Wx_c, (void*)&Wh_c, (void*)&Wm_c, (void*)&b_c,
                     (void*)&out,
                     (void*)&WTa, (void*)&WTp2, (void*)&WTp1, (void*)&WTc,
                     (void*)&embbf, (void*)&hbf, (void*)&hmbf,
                     (void*)&ctask, (void*)&cmain, (void*)&p2w, (void*)&partial,
                     (void*)&hNf, (void*)&bar };
    hipLaunchCooperativeKernel((void*)fused_all, dim3(256), dim3(512), args, 0, stream);
}